// Round 5
// baseline (6887.947 us; speedup 1.0000x reference)
//
#include <hip/hip_runtime.h>
#include <math.h>

// Problem constants (match reference)
#define NN 50000
#define SEQ 52
#define FIN 16
#define HD 128
#define NEG_SLOPE 0.2f

typedef short bf16x8 __attribute__((ext_vector_type(8)));   // 8 bf16 (4 VGPRs)
typedef float f32x16 __attribute__((ext_vector_type(16)));  // 32x32 MFMA C/D

__device__ __forceinline__ short f2bf(float x) {
    unsigned u = __float_as_uint(x);
    u += 0x7fffu + ((u >> 16) & 1u);   // round-to-nearest-even
    return (short)(u >> 16);
}
__device__ __forceinline__ float b2f(short s) {
    return __uint_as_float(((unsigned)(unsigned short)s) << 16);
}

// ---------------------------------------------------------------------------
// CSR build kernels (run once per launch; graph is static across timesteps)
// ---------------------------------------------------------------------------
__global__ void deg_init_kernel(int* deg, int n) {
    int i = blockIdx.x * blockDim.x + threadIdx.x;
    if (i < n) deg[i] = 1;  // self-loop
}

__global__ void deg_count_kernel(const int* __restrict__ dst, int* deg, int e) {
    int i = blockIdx.x * blockDim.x + threadIdx.x;
    if (i < e) atomicAdd(&deg[dst[i]], 1);
}

__global__ __launch_bounds__(1024) void scan_kernel(const int* __restrict__ deg,
                                                    int* row_ptr, int n) {
    __shared__ int buf[1024];
    __shared__ int carry;
    int tid = threadIdx.x;
    if (tid == 0) carry = 0;
    __syncthreads();
    for (int base = 0; base < n; base += 1024) {
        int i = base + tid;
        int v = (i < n) ? deg[i] : 0;
        buf[tid] = v;
        __syncthreads();
        for (int off = 1; off < 1024; off <<= 1) {
            int t = (tid >= off) ? buf[tid - off] : 0;
            __syncthreads();
            buf[tid] += t;
            __syncthreads();
        }
        if (i < n) row_ptr[i] = carry + buf[tid] - v;  // exclusive
        __syncthreads();
        if (tid == 1023) carry += buf[1023];
        __syncthreads();
    }
    if (tid == 0) row_ptr[n] = carry;
}

// also records dst_slot (owner node of each CSR slot) for the per-step
// edge-weight pre-pass
__global__ void selfloop_kernel(const int* __restrict__ row_ptr, int* cursor,
                                int* col, int* dst_slot, int n) {
    int i = blockIdx.x * blockDim.x + threadIdx.x;
    if (i < n) {
        int p = row_ptr[i];
        col[p] = i;          // self-loop first
        dst_slot[p] = i;
        cursor[i] = p + 1;
    }
}

__global__ void scatter_kernel(const int* __restrict__ src, const int* __restrict__ dst,
                               int* cursor, int* col, int* dst_slot, int e) {
    int i = blockIdx.x * blockDim.x + threadIdx.x;
    if (i < e) {
        int d = dst[i];
        int p = atomicAdd(&cursor[d], 1);
        col[p] = src[i];
        dst_slot[p] = d;
    }
}

// ---------------------------------------------------------------------------
// Pack W_ih/W_hh into MFMA B-fragment order, split bf16 hi/lo.
// Index: ((((g*4+slab)*8+ks)*4+which)*64+lane)*8 shorts,
//   which: 0=ih_hi 1=ih_lo 2=hh_hi 3=hh_lo
//   col = slab*32 + (lane&31), kcol = ks*16 + (lane>>5)*8
// ---------------------------------------------------------------------------
__global__ void wpack_kernel(const float* __restrict__ Wi, const float* __restrict__ Wh,
                             short* __restrict__ wfrag) {
    int idx = blockIdx.x * blockDim.x + threadIdx.x;
    if (idx >= 3 * 4 * 8 * 4 * 64) return;
    int lane = idx & 63;
    int which = (idx >> 6) & 3;
    int ks = (idx >> 8) & 7;
    int slab = (idx >> 11) & 3;
    int g = idx >> 13;
    int col = slab * 32 + (lane & 31);
    int kcol = ks * 16 + (lane >> 5) * 8;
    const float* Wsrc = (which < 2) ? Wi : Wh;
    const float* row = Wsrc + (size_t)(g * HD + col) * HD + kcol;
    short* dstp = wfrag + (size_t)idx * 8;
    bool lo = (which & 1);
#pragma unroll
    for (int e = 0; e < 8; ++e) {
        float v = row[e];
        short hi = f2bf(v);
        dstp[e] = lo ? f2bf(v - b2f(hi)) : hi;
    }
}

// ---------------------------------------------------------------------------
// Per-timestep kernels
// ---------------------------------------------------------------------------

// xp = x_t @ Wg (stored bf16); a_s = xp.att_src ; a_d = xp.att_dst
__global__ __launch_bounds__(256) void xp_kernel(
    const float* __restrict__ x, const float* __restrict__ Wg,
    const float* __restrict__ att_src, const float* __restrict__ att_dst,
    unsigned* __restrict__ xpb, float* __restrict__ a_s, float* __restrict__ a_d, int n) {
    int wave = (blockIdx.x * blockDim.x + threadIdx.x) >> 6;
    int lane = threadIdx.x & 63;
    if (wave >= n) return;
    const float* xr = x + (size_t)wave * FIN;
    float xv[FIN];
#pragma unroll
    for (int k = 0; k < FIN; ++k) xv[k] = xr[k];
    int c0 = 2 * lane, c1 = 2 * lane + 1;
    float v0 = 0.f, v1 = 0.f;
#pragma unroll
    for (int k = 0; k < FIN; ++k) {
        v0 += xv[k] * Wg[k * HD + c0];
        v1 += xv[k] * Wg[k * HD + c1];
    }
    unsigned p = (unsigned)(unsigned short)f2bf(v0) |
                 ((unsigned)(unsigned short)f2bf(v1) << 16);
    xpb[(size_t)wave * 64 + lane] = p;
    float s = v0 * att_src[c0] + v1 * att_src[c1];
    float d = v0 * att_dst[c0] + v1 * att_dst[c1];
#pragma unroll
    for (int off = 32; off; off >>= 1) {
        s += __shfl_xor(s, off);
        d += __shfl_xor(d, off);
    }
    if (lane == 0) { a_s[wave] = s; a_d[wave] = d; }
}

// ---------------------------------------------------------------------------
// Fused GAT + GRU kernel (R5).
// Block = 256 threads = 4 waves, owns 32 dst nodes (n0..n0+31).
//
// Phase 0 (NEW): block-wide edge-weight pre-pass. The block's nodes own the
//   contiguous CSR slot range [row_ptr[n0], row_ptr[n0+32]) (~544 slots avg).
//   All 256 threads compute wgt = exp(leaky(a_s[col[p]] + a_d[dst_slot[p]]))
//   stride-256: 256 gathers in flight -> ~2-3 round trips for the WHOLE
//   block (was 2 serial dependent trips PER NODE). Weights go to a global
//   scratch (block-local reuse; same-CU L1/L2-hot; L1 is invalidated at
//   dispatch start so no cross-step staleness).
//
// GAT phase: 16-lane group per node, 2 nodes/group. Per <=16-edge chunk:
//   col/wgt are coalesced L1-hot reads; the FULL chunk's rows stream 16-deep
//   (16 bf16x8 = 64 VGPRs live, GAT-phase only -> under the GRU VGPR peak),
//   (src,wgt) broadcast group-internally via __shfl (source lane is always
//   in the reader's group and active under the same u<cnt guard).
//   ~ceil(deg/16)=2 memory round trips per node (was ~5) and no exp/leaky
//   on the low-occupancy critical path.
//   Epilogue: relu+bias, split-bf16, direct LDS store in MFMA A-frag layout.
//
// h staging: global loads issued before phase 0, consumed after GAT phase.
// GRU phase: R1-proven core unchanged (triple-buffered weights, 4 accs).
// ---------------------------------------------------------------------------
__global__ __launch_bounds__(256, 2) void gatgru_kernel(
    const int* __restrict__ row_ptr, const int* __restrict__ col,
    const int* __restrict__ dst_slot, float* __restrict__ wgt_g,
    const float* __restrict__ a_s, const float* __restrict__ a_d,
    const short* __restrict__ xpb, const float* __restrict__ bias_g,
    float* __restrict__ h, const short* __restrict__ wfrag,
    const float* __restrict__ b_ih, const float* __restrict__ b_hh, int n) {
    __shared__ bf16x8 sSH[512];  // spatial hi (gat output, A-frag layout)
    __shared__ bf16x8 sSL[512];  // spatial lo
    __shared__ bf16x8 sHH[512];  // h hi
    __shared__ bf16x8 sHL[512];  // h lo

    int t = threadIdx.x;
    int lane = t & 63;
    int w = t >> 6;
    int n0 = blockIdx.x * 32;

    // ---- issue h loads early (consumed after gat phase) ----
    float h8[2][8];
#pragma unroll
    for (int q = 0; q < 2; ++q) {
        int ks = w * 2 + q;
        int row = n0 + (lane & 31);
        if (row >= n) row = n - 1;
        int kcol = ks * 16 + (lane >> 5) * 8;
        const float* hp = h + (size_t)row * HD + kcol;
        *(float4*)(h8[q]) = *(const float4*)(hp);
        *(float4*)(h8[q] + 4) = *(const float4*)(hp + 4);
    }

    // ---- phase 0: block-wide edge weights for this block's slot range ----
    int nend = (n0 + 32 < n) ? (n0 + 32) : n;
    int rp0 = row_ptr[n0];
    int rp1 = row_ptr[nend];
    for (int p = rp0 + t; p < rp1; p += 256) {
        float e = a_s[col[p]] + a_d[dst_slot[p]];
        e = (e > 0.f) ? e : NEG_SLOPE * e;
        wgt_g[p] = __expf(e);
    }
    __syncthreads();   // wgt_g visible block-wide (same CU; L2 coherence point)

    // ---- GAT phase: 16-lane group per node, 2 nodes per group ----
    int g = t >> 4;          // group 0..15
    int fg = t & 15;         // feature lane: features fg*8..fg*8+7
    int glane = lane & 0x30; // group base lane within wave

#pragma unroll
    for (int nn = 0; nn < 2; ++nn) {
        int nl = g + nn * 16;   // local node 0..31
        int nd = n0 + nl;
        int sidx = (fg >> 1) * 64 + (fg & 1) * 32 + nl;  // A-frag LDS slot
        if (nd < n) {
            int start = row_ptr[nd], end = row_ptr[nd + 1];
            float acc[8] = {0.f, 0.f, 0.f, 0.f, 0.f, 0.f, 0.f, 0.f};
            float dpart = 0.f;
            for (int base = start; base < end; base += 16) {
                int cnt = end - base;
                if (cnt > 16) cnt = 16;
                // coalesced L1-hot reads of this chunk's col/wgt
                int s = 0;
                float wi = 0.f;
                if (fg < cnt) {
                    s = col[base + fg];
                    wi = wgt_g[base + fg];
                }
                dpart += wi;
                // stream the whole chunk: up to 16 row loads in flight
                bf16x8 r[16];
#pragma unroll
                for (int u = 0; u < 16; ++u) {
                    if (u < cnt) {
                        int si = __shfl(s, glane | u);
                        r[u] = *(const bf16x8*)(xpb + (size_t)si * HD + fg * 8);
                    }
                }
#pragma unroll
                for (int u = 0; u < 16; ++u) {
                    if (u < cnt) {
                        float wu = __shfl(wi, glane | u);
#pragma unroll
                        for (int j = 0; j < 8; ++j) acc[j] += wu * b2f(r[u][j]);
                    }
                }
            }
            // denom reduce across the 16-lane group
            dpart += __shfl_xor(dpart, 8);
            dpart += __shfl_xor(dpart, 4);
            dpart += __shfl_xor(dpart, 2);
            dpart += __shfl_xor(dpart, 1);
            float inv = __fdividef(1.f, dpart);
            bf16x8 sh, sl;
#pragma unroll
            for (int j = 0; j < 8; ++j) {
                float o = acc[j] * inv + bias_g[fg * 8 + j];
                o = fmaxf(o, 0.f);
                short hi = f2bf(o);
                sh[j] = hi;
                sl[j] = f2bf(o - b2f(hi));
            }
            sSH[sidx] = sh;
            sSL[sidx] = sl;
        } else {
            bf16x8 z;
#pragma unroll
            for (int j = 0; j < 8; ++j) z[j] = 0;
            sSH[sidx] = z;
            sSL[sidx] = z;
        }
    }

    // ---- convert + write h tiles (loads drained long ago) ----
#pragma unroll
    for (int q = 0; q < 2; ++q) {
        int ks = w * 2 + q;
        bf16x8 hh, hl;
#pragma unroll
        for (int j = 0; j < 8; ++j) {
            short b = f2bf(h8[q][j]);
            hh[j] = b;
            hl[j] = f2bf(h8[q][j] - b2f(b));
        }
        int li = ks * 64 + lane;
        sHH[li] = hh;
        sHL[li] = hl;
    }
    __syncthreads();

    // ---- GRU phase (R1 core) ----
    int j0 = w * 32;
    int cj = lane & 31;       // column within wave's 32-col slab
    int kh = lane >> 5;       // k-half for frags

    f32x16 arz[2], ain, ahn;  // r, z (merged i+h), i_n, h_n
#pragma unroll
    for (int r = 0; r < 16; ++r) {
        arz[0][r] = 0.f; arz[1][r] = 0.f; ain[r] = 0.f; ahn[r] = 0.f;
    }

    // fragment-ordered weight base for this wave: + g*65536 + ks*2048 + which*512
    const short* wb = wfrag + (size_t)w * 16384 + (size_t)lane * 8;

    // weight triple buffer: [buf][g*4 + which]
    bf16x8 wv[3][12];
#pragma unroll
    for (int p = 0; p < 2; ++p) {
#pragma unroll
        for (int gg = 0; gg < 3; ++gg) {
#pragma unroll
            for (int q = 0; q < 4; ++q)
                wv[p][gg * 4 + q] = *(const bf16x8*)(wb + gg * 65536 + p * 2048 + q * 512);
        }
    }

#pragma unroll
    for (int ks = 0; ks < 8; ++ks) {
        int cur = ks % 3;
        if (ks < 6) {
            int nxt = (ks + 2) % 3;
#pragma unroll
            for (int gg = 0; gg < 3; ++gg) {
#pragma unroll
                for (int q = 0; q < 4; ++q)
                    wv[nxt][gg * 4 + q] =
                        *(const bf16x8*)(wb + gg * 65536 + (ks + 2) * 2048 + q * 512);
            }
        }
        int li = ks * 64 + lane;
        bf16x8 aSH = sSH[li];
        bf16x8 aSL = sSL[li];
        bf16x8 aHH = sHH[li];
        bf16x8 aHL = sHL[li];
        // r and z gates: both GEMMs into one accumulator
#pragma unroll
        for (int gg = 0; gg < 2; ++gg) {
            bf16x8 wih = wv[cur][gg * 4 + 0];
            bf16x8 wil = wv[cur][gg * 4 + 1];
            bf16x8 whh = wv[cur][gg * 4 + 2];
            bf16x8 whl = wv[cur][gg * 4 + 3];
            arz[gg] = __builtin_amdgcn_mfma_f32_32x32x16_bf16(aSH, wih, arz[gg], 0, 0, 0);
            arz[gg] = __builtin_amdgcn_mfma_f32_32x32x16_bf16(aHH, whh, arz[gg], 0, 0, 0);
            arz[gg] = __builtin_amdgcn_mfma_f32_32x32x16_bf16(aSL, wih, arz[gg], 0, 0, 0);
            arz[gg] = __builtin_amdgcn_mfma_f32_32x32x16_bf16(aHL, whh, arz[gg], 0, 0, 0);
            arz[gg] = __builtin_amdgcn_mfma_f32_32x32x16_bf16(aSH, wil, arz[gg], 0, 0, 0);
            arz[gg] = __builtin_amdgcn_mfma_f32_32x32x16_bf16(aHH, whl, arz[gg], 0, 0, 0);
        }
        // n gate: separate accs (r multiplies h_n before tanh)
        {
            bf16x8 wih = wv[cur][8];
            bf16x8 wil = wv[cur][9];
            bf16x8 whh = wv[cur][10];
            bf16x8 whl = wv[cur][11];
            ain = __builtin_amdgcn_mfma_f32_32x32x16_bf16(aSH, wih, ain, 0, 0, 0);
            ahn = __builtin_amdgcn_mfma_f32_32x32x16_bf16(aHH, whh, ahn, 0, 0, 0);
            ain = __builtin_amdgcn_mfma_f32_32x32x16_bf16(aSL, wih, ain, 0, 0, 0);
            ahn = __builtin_amdgcn_mfma_f32_32x32x16_bf16(aHL, whh, ahn, 0, 0, 0);
            ain = __builtin_amdgcn_mfma_f32_32x32x16_bf16(aSH, wil, ain, 0, 0, 0);
            ahn = __builtin_amdgcn_mfma_f32_32x32x16_bf16(aHH, whl, ahn, 0, 0, 0);
        }
    }

    // ---- wave-local GRU elementwise + h write ----
    int j = j0 + cj;
    float brz0 = b_ih[j] + b_hh[j];
    float brz1 = b_ih[HD + j] + b_hh[HD + j];
    float bin_ = b_ih[2 * HD + j];
    float bhn = b_hh[2 * HD + j];
    const short* hhs = (const short*)sHH;
    const short* hls = (const short*)sHL;
    int ksj = j >> 4, halfj = (j >> 3) & 1, ej = j & 7;

#pragma unroll
    for (int r = 0; r < 16; ++r) {
        int nl = (r & 3) + 8 * (r >> 2) + 4 * kh;  // C/D row mapping (m74/m101)
        int node = n0 + nl;
        if (node < n) {
            float rr = __fdividef(1.f, 1.f + __expf(-(arz[0][r] + brz0)));
            float zz = __fdividef(1.f, 1.f + __expf(-(arz[1][r] + brz1)));
            float u = ain[r] + bin_ + rr * (ahn[r] + bhn);
            float ex = __expf(2.f * u);
            float nn2 = 1.f - __fdividef(2.f, ex + 1.f);  // tanh(u)
            int li = (ksj * 64 + nl + 32 * halfj) * 8 + ej;
            float hold = b2f(hhs[li]) + b2f(hls[li]);
            h[(size_t)node * HD + j] = (1.f - zz) * nn2 + zz * hold;
        }
    }
}

// out[n] = h[n] . W_fc + b_fc   (one wave per node)
__global__ __launch_bounds__(256) void fc_kernel(
    const float* __restrict__ h, const float* __restrict__ W_fc,
    const float* __restrict__ b_fc, float* __restrict__ out, int n) {
    int wave = (blockIdx.x * blockDim.x + threadIdx.x) >> 6;
    int lane = threadIdx.x & 63;
    if (wave >= n) return;
    float v = h[(size_t)wave * HD + lane] * W_fc[lane] +
              h[(size_t)wave * HD + lane + 64] * W_fc[lane + 64];
#pragma unroll
    for (int off = 32; off; off >>= 1) v += __shfl_xor(v, off);
    if (lane == 0) out[wave] = v + b_fc[0];
}

// ---------------------------------------------------------------------------
extern "C" void kernel_launch(void* const* d_in, const int* in_sizes, int n_in,
                              void* d_out, int out_size, void* d_ws, size_t ws_size,
                              hipStream_t stream) {
    const float* x_seq   = (const float*)d_in[0];
    const int*   ei      = (const int*)d_in[1];
    const float* Wg      = (const float*)d_in[2];
    const float* att_src = (const float*)d_in[3];
    const float* att_dst = (const float*)d_in[4];
    const float* bias_g  = (const float*)d_in[5];
    const float* W_ih    = (const float*)d_in[6];
    const float* W_hh    = (const float*)d_in[7];
    const float* b_ih    = (const float*)d_in[8];
    const float* b_hh    = (const float*)d_in[9];
    const float* W_fc    = (const float*)d_in[10];
    const float* b_fc    = (const float*)d_in[11];
    float* out = (float*)d_out;

    const int N = NN;
    const int E = in_sizes[1] / 2;
    const int* src = ei;
    const int* dst = ei + E;

    // workspace layout
    char* w = (char*)d_ws;
    size_t off = 0;
    auto alloc = [&](size_t bytes) {
        char* p = w + off;
        off = (off + bytes + 255) & ~(size_t)255;
        return p;
    };
    int*   deg      = (int*)alloc((size_t)N * 4);
    int*   row_ptr  = (int*)alloc((size_t)(N + 1) * 4);
    int*   cursor   = (int*)alloc((size_t)N * 4);
    int*   col      = (int*)alloc((size_t)(E + N) * 4);
    int*   dst_slot = (int*)alloc((size_t)(E + N) * 4);
    float* wgt_g    = (float*)alloc((size_t)(E + N) * 4);
    float* a_s      = (float*)alloc((size_t)N * 4);
    float* a_d      = (float*)alloc((size_t)N * 4);
    unsigned* xpb   = (unsigned*)alloc((size_t)N * 64 * 4);   // bf16 xp [N][128]
    float* hbuf     = (float*)alloc((size_t)N * HD * 4);
    short* wfrag    = (short*)alloc((size_t)3 * 4 * 8 * 4 * 64 * 8 * 2);  // 393KB

    // h0 = 0
    hipMemsetAsync(hbuf, 0, (size_t)N * HD * 4, stream);

    // CSR build + weight pack (once per launch)
    deg_init_kernel<<<(N + 255) / 256, 256, 0, stream>>>(deg, N);
    deg_count_kernel<<<(E + 255) / 256, 256, 0, stream>>>(dst, deg, E);
    scan_kernel<<<1, 1024, 0, stream>>>(deg, row_ptr, N);
    selfloop_kernel<<<(N + 255) / 256, 256, 0, stream>>>(row_ptr, cursor, col,
                                                         dst_slot, N);
    scatter_kernel<<<(E + 255) / 256, 256, 0, stream>>>(src, dst, cursor, col,
                                                        dst_slot, E);
    wpack_kernel<<<(24576 + 255) / 256, 256, 0, stream>>>(W_ih, W_hh, wfrag);

    int node_wave_blocks = (N * 64 + 255) / 256;  // one wave per node
    int fused_blocks = (N + 31) / 32;             // 32-node fused tiles

    for (int t = 0; t < SEQ; ++t) {
        const float* xt = x_seq + (size_t)t * N * FIN;
        xp_kernel<<<node_wave_blocks, 256, 0, stream>>>(xt, Wg, att_src, att_dst,
                                                        xpb, a_s, a_d, N);
        gatgru_kernel<<<fused_blocks, 256, 0, stream>>>(row_ptr, col, dst_slot,
                                                        wgt_g, a_s, a_d,
                                                        (const short*)xpb, bias_g,
                                                        hbuf, wfrag, b_ih, b_hh, N);
    }
    fc_kernel<<<node_wave_blocks, 256, 0, stream>>>(hbuf, W_fc, b_fc, out, N);
}

// Round 6
// 6124.556 us; speedup vs baseline: 1.1246x; 1.1246x over previous
//
#include <hip/hip_runtime.h>
#include <math.h>

// Problem constants (match reference)
#define NN 50000
#define SEQ 52
#define FIN 16
#define HD 128
#define NEG_SLOPE 0.2f

typedef short bf16x8 __attribute__((ext_vector_type(8)));   // 8 bf16 (4 VGPRs)
typedef float f32x16 __attribute__((ext_vector_type(16)));  // 32x32 MFMA C/D

__device__ __forceinline__ short f2bf(float x) {
    unsigned u = __float_as_uint(x);
    u += 0x7fffu + ((u >> 16) & 1u);   // round-to-nearest-even
    return (short)(u >> 16);
}
__device__ __forceinline__ float b2f(short s) {
    return __uint_as_float(((unsigned)(unsigned short)s) << 16);
}

// ---------------------------------------------------------------------------
// CSR build kernels (run once per launch; graph is static across timesteps)
// ---------------------------------------------------------------------------
__global__ void deg_init_kernel(int* deg, int n) {
    int i = blockIdx.x * blockDim.x + threadIdx.x;
    if (i < n) deg[i] = 1;  // self-loop
}

__global__ void deg_count_kernel(const int* __restrict__ dst, int* deg, int e) {
    int i = blockIdx.x * blockDim.x + threadIdx.x;
    if (i < e) atomicAdd(&deg[dst[i]], 1);
}

__global__ __launch_bounds__(1024) void scan_kernel(const int* __restrict__ deg,
                                                    int* row_ptr, int n) {
    __shared__ int buf[1024];
    __shared__ int carry;
    int tid = threadIdx.x;
    if (tid == 0) carry = 0;
    __syncthreads();
    for (int base = 0; base < n; base += 1024) {
        int i = base + tid;
        int v = (i < n) ? deg[i] : 0;
        buf[tid] = v;
        __syncthreads();
        for (int off = 1; off < 1024; off <<= 1) {
            int t = (tid >= off) ? buf[tid - off] : 0;
            __syncthreads();
            buf[tid] += t;
            __syncthreads();
        }
        if (i < n) row_ptr[i] = carry + buf[tid] - v;  // exclusive
        __syncthreads();
        if (tid == 1023) carry += buf[1023];
        __syncthreads();
    }
    if (tid == 0) row_ptr[n] = carry;
}

__global__ void selfloop_kernel(const int* __restrict__ row_ptr, int* cursor,
                                int* col, int n) {
    int i = blockIdx.x * blockDim.x + threadIdx.x;
    if (i < n) {
        int p = row_ptr[i];
        col[p] = i;          // self-loop first
        cursor[i] = p + 1;
    }
}

__global__ void scatter_kernel(const int* __restrict__ src, const int* __restrict__ dst,
                               int* cursor, int* col, int e) {
    int i = blockIdx.x * blockDim.x + threadIdx.x;
    if (i < e) {
        int p = atomicAdd(&cursor[dst[i]], 1);
        col[p] = src[i];
    }
}

// ---------------------------------------------------------------------------
// Pack W_ih/W_hh into MFMA B-fragment order, split bf16 hi/lo.
// Index: ((((g*4+slab)*8+ks)*4+which)*64+lane)*8 shorts,
//   which: 0=ih_hi 1=ih_lo 2=hh_hi 3=hh_lo
//   col = slab*32 + (lane&31), kcol = ks*16 + (lane>>5)*8
// ---------------------------------------------------------------------------
__global__ void wpack_kernel(const float* __restrict__ Wi, const float* __restrict__ Wh,
                             short* __restrict__ wfrag) {
    int idx = blockIdx.x * blockDim.x + threadIdx.x;
    if (idx >= 3 * 4 * 8 * 4 * 64) return;
    int lane = idx & 63;
    int which = (idx >> 6) & 3;
    int ks = (idx >> 8) & 7;
    int slab = (idx >> 11) & 3;
    int g = idx >> 13;
    int col = slab * 32 + (lane & 31);
    int kcol = ks * 16 + (lane >> 5) * 8;
    const float* Wsrc = (which < 2) ? Wi : Wh;
    const float* row = Wsrc + (size_t)(g * HD + col) * HD + kcol;
    short* dstp = wfrag + (size_t)idx * 8;
    bool lo = (which & 1);
#pragma unroll
    for (int e = 0; e < 8; ++e) {
        float v = row[e];
        short hi = f2bf(v);
        dstp[e] = lo ? f2bf(v - b2f(hi)) : hi;
    }
}

// ---------------------------------------------------------------------------
// Per-timestep kernels
// ---------------------------------------------------------------------------

// xp = x_t @ Wg (stored bf16); a_s = xp.att_src ; a_d = xp.att_dst
// Used ONCE as prologue for t=0; steps 1..51 are produced by gatgru's tail.
__global__ __launch_bounds__(256) void xp_kernel(
    const float* __restrict__ x, const float* __restrict__ Wg,
    const float* __restrict__ att_src, const float* __restrict__ att_dst,
    unsigned* __restrict__ xpb, float* __restrict__ a_s, float* __restrict__ a_d, int n) {
    int wave = (blockIdx.x * blockDim.x + threadIdx.x) >> 6;
    int lane = threadIdx.x & 63;
    if (wave >= n) return;
    const float* xr = x + (size_t)wave * FIN;
    float xv[FIN];
#pragma unroll
    for (int k = 0; k < FIN; ++k) xv[k] = xr[k];
    int c0 = 2 * lane, c1 = 2 * lane + 1;
    float v0 = 0.f, v1 = 0.f;
#pragma unroll
    for (int k = 0; k < FIN; ++k) {
        v0 += xv[k] * Wg[k * HD + c0];
        v1 += xv[k] * Wg[k * HD + c1];
    }
    unsigned p = (unsigned)(unsigned short)f2bf(v0) |
                 ((unsigned)(unsigned short)f2bf(v1) << 16);
    xpb[(size_t)wave * 64 + lane] = p;
    float s = v0 * att_src[c0] + v1 * att_src[c1];
    float d = v0 * att_dst[c0] + v1 * att_dst[c1];
#pragma unroll
    for (int off = 32; off; off >>= 1) {
        s += __shfl_xor(s, off);
        d += __shfl_xor(d, off);
    }
    if (lane == 0) { a_s[wave] = s; a_d[wave] = d; }
}

// ---------------------------------------------------------------------------
// Fused GAT + GRU (+ next-step xp tail) kernel (R6 = R4 + xp fusion).
// Block = 256 threads = 4 waves, owns 32 dst nodes (n0..n0+31).
//
// GAT phase (R4-proven): 16-lane group per node, 2 nodes/group. Per <=16-edge
//   chunk: lane e gathers col/a_s/score in parallel; rows stream 4-deep with
//   group-internal exec-uniform __shfl broadcasts of (src,wgt). Epilogue:
//   relu+bias -> split-bf16 -> LDS in MFMA A-frag layout (spatial never
//   touches global memory).
// h staging: global loads issued first, consumed after the GAT phase.
// GRU phase (R1-proven): triple-buffered weight prefetch, 4 accumulators.
//
// xp TAIL (NEW): after the h write, registers are dead and MFMA waves drain;
//   each block computes NEXT timestep's xp for its own 32 nodes into the
//   double-buffered xpb/a_s/a_d. 8 threads per node, 16 cols per thread;
//   Wg (8KB) is L1-hot. Removes the separate xp launch for t=1..51 (104->52
//   dispatches) and overlaps xp work with other blocks' GAT/GRU phases.
//   Safety: stream serialization guarantees gatgru(t-1) fully wrote
//   xpb[cur] before gatgru(t) reads it; the tail writes only xpb[nxt].
// ---------------------------------------------------------------------------
__global__ __launch_bounds__(256, 2) void gatgru_kernel(
    const int* __restrict__ row_ptr, const int* __restrict__ col,
    const float* __restrict__ a_s, const float* __restrict__ a_d,
    const short* __restrict__ xpb, const float* __restrict__ bias_g,
    float* __restrict__ h, const short* __restrict__ wfrag,
    const float* __restrict__ b_ih, const float* __restrict__ b_hh, int n,
    const float* __restrict__ x_next, const float* __restrict__ Wg,
    const float* __restrict__ att_src, const float* __restrict__ att_dst,
    unsigned* __restrict__ xpb_next, float* __restrict__ a_s_next,
    float* __restrict__ a_d_next) {
    __shared__ bf16x8 sSH[512];  // spatial hi (gat output, A-frag layout)
    __shared__ bf16x8 sSL[512];  // spatial lo
    __shared__ bf16x8 sHH[512];  // h hi
    __shared__ bf16x8 sHL[512];  // h lo

    int t = threadIdx.x;
    int lane = t & 63;
    int w = t >> 6;
    int n0 = blockIdx.x * 32;

    // ---- issue h loads early (consumed after gat phase) ----
    float h8[2][8];
#pragma unroll
    for (int q = 0; q < 2; ++q) {
        int ks = w * 2 + q;
        int row = n0 + (lane & 31);
        if (row >= n) row = n - 1;
        int kcol = ks * 16 + (lane >> 5) * 8;
        const float* hp = h + (size_t)row * HD + kcol;
        *(float4*)(h8[q]) = *(const float4*)(hp);
        *(float4*)(h8[q] + 4) = *(const float4*)(hp + 4);
    }

    // ---- GAT phase: 16-lane group per node, 2 nodes per group ----
    int g = t >> 4;          // group 0..15
    int fg = t & 15;         // feature lane: features fg*8..fg*8+7
    int glane = lane & 0x30; // group base lane within wave

#pragma unroll
    for (int nn = 0; nn < 2; ++nn) {
        int nl = g + nn * 16;   // local node 0..31
        int nd = n0 + nl;
        int sidx = (fg >> 1) * 64 + (fg & 1) * 32 + nl;  // A-frag LDS slot
        if (nd < n) {
            int start = row_ptr[nd], end = row_ptr[nd + 1];
            float ad = a_d[nd];
            float acc[8] = {0.f, 0.f, 0.f, 0.f, 0.f, 0.f, 0.f, 0.f};
            float dpart = 0.f;
            for (int base = start; base < end; base += 16) {
                int cnt = end - base;
                if (cnt > 16) cnt = 16;
                // phase 1: lane fg gathers edge base+fg
                int s = 0;
                float wgt = 0.f;
                if (fg < cnt) {
                    s = col[base + fg];
                    float e = a_s[s] + ad;
                    e = (e > 0.f) ? e : NEG_SLOPE * e;
                    wgt = __expf(e);
                }
                dpart += wgt;
                // phase 2: stream rows, 4 in flight, group-internal shfl
                for (int k = 0; k < cnt; k += 4) {
                    int si[4];
                    float wt[4];
#pragma unroll
                    for (int u = 0; u < 4; ++u) {
                        int c = k + u;
                        int cc = (c < cnt) ? c : 0;
                        si[u] = __shfl(s, glane | cc);
                        wt[u] = __shfl(wgt, glane | cc);
                        if (c >= cnt) wt[u] = 0.f;
                    }
                    bf16x8 r[4];
#pragma unroll
                    for (int u = 0; u < 4; ++u)
                        r[u] = *(const bf16x8*)(xpb + (size_t)si[u] * HD + fg * 8);
#pragma unroll
                    for (int u = 0; u < 4; ++u)
#pragma unroll
                        for (int j = 0; j < 8; ++j) acc[j] += wt[u] * b2f(r[u][j]);
                }
            }
            // denom reduce across the 16-lane group
            dpart += __shfl_xor(dpart, 8);
            dpart += __shfl_xor(dpart, 4);
            dpart += __shfl_xor(dpart, 2);
            dpart += __shfl_xor(dpart, 1);
            float inv = __fdividef(1.f, dpart);
            bf16x8 sh, sl;
#pragma unroll
            for (int j = 0; j < 8; ++j) {
                float o = acc[j] * inv + bias_g[fg * 8 + j];
                o = fmaxf(o, 0.f);
                short hi = f2bf(o);
                sh[j] = hi;
                sl[j] = f2bf(o - b2f(hi));
            }
            sSH[sidx] = sh;
            sSL[sidx] = sl;
        } else {
            bf16x8 z;
#pragma unroll
            for (int j = 0; j < 8; ++j) z[j] = 0;
            sSH[sidx] = z;
            sSL[sidx] = z;
        }
    }

    // ---- convert + write h tiles (loads drained long ago) ----
#pragma unroll
    for (int q = 0; q < 2; ++q) {
        int ks = w * 2 + q;
        bf16x8 hh, hl;
#pragma unroll
        for (int j = 0; j < 8; ++j) {
            short b = f2bf(h8[q][j]);
            hh[j] = b;
            hl[j] = f2bf(h8[q][j] - b2f(b));
        }
        int li = ks * 64 + lane;
        sHH[li] = hh;
        sHL[li] = hl;
    }
    __syncthreads();

    // ---- GRU phase (R1 core) ----
    int j0 = w * 32;
    int cj = lane & 31;       // column within wave's 32-col slab
    int kh = lane >> 5;       // k-half for frags

    f32x16 arz[2], ain, ahn;  // r, z (merged i+h), i_n, h_n
#pragma unroll
    for (int r = 0; r < 16; ++r) {
        arz[0][r] = 0.f; arz[1][r] = 0.f; ain[r] = 0.f; ahn[r] = 0.f;
    }

    // fragment-ordered weight base for this wave: + g*65536 + ks*2048 + which*512
    const short* wb = wfrag + (size_t)w * 16384 + (size_t)lane * 8;

    // weight triple buffer: [buf][g*4 + which]
    bf16x8 wv[3][12];
#pragma unroll
    for (int p = 0; p < 2; ++p) {
#pragma unroll
        for (int gg = 0; gg < 3; ++gg) {
#pragma unroll
            for (int q = 0; q < 4; ++q)
                wv[p][gg * 4 + q] = *(const bf16x8*)(wb + gg * 65536 + p * 2048 + q * 512);
        }
    }

#pragma unroll
    for (int ks = 0; ks < 8; ++ks) {
        int cur = ks % 3;
        if (ks < 6) {
            int nxt = (ks + 2) % 3;
#pragma unroll
            for (int gg = 0; gg < 3; ++gg) {
#pragma unroll
                for (int q = 0; q < 4; ++q)
                    wv[nxt][gg * 4 + q] =
                        *(const bf16x8*)(wb + gg * 65536 + (ks + 2) * 2048 + q * 512);
            }
        }
        int li = ks * 64 + lane;
        bf16x8 aSH = sSH[li];
        bf16x8 aSL = sSL[li];
        bf16x8 aHH = sHH[li];
        bf16x8 aHL = sHL[li];
        // r and z gates: both GEMMs into one accumulator
#pragma unroll
        for (int gg = 0; gg < 2; ++gg) {
            bf16x8 wih = wv[cur][gg * 4 + 0];
            bf16x8 wil = wv[cur][gg * 4 + 1];
            bf16x8 whh = wv[cur][gg * 4 + 2];
            bf16x8 whl = wv[cur][gg * 4 + 3];
            arz[gg] = __builtin_amdgcn_mfma_f32_32x32x16_bf16(aSH, wih, arz[gg], 0, 0, 0);
            arz[gg] = __builtin_amdgcn_mfma_f32_32x32x16_bf16(aHH, whh, arz[gg], 0, 0, 0);
            arz[gg] = __builtin_amdgcn_mfma_f32_32x32x16_bf16(aSL, wih, arz[gg], 0, 0, 0);
            arz[gg] = __builtin_amdgcn_mfma_f32_32x32x16_bf16(aHL, whh, arz[gg], 0, 0, 0);
            arz[gg] = __builtin_amdgcn_mfma_f32_32x32x16_bf16(aSH, wil, arz[gg], 0, 0, 0);
            arz[gg] = __builtin_amdgcn_mfma_f32_32x32x16_bf16(aHH, whl, arz[gg], 0, 0, 0);
        }
        // n gate: separate accs (r multiplies h_n before tanh)
        {
            bf16x8 wih = wv[cur][8];
            bf16x8 wil = wv[cur][9];
            bf16x8 whh = wv[cur][10];
            bf16x8 whl = wv[cur][11];
            ain = __builtin_amdgcn_mfma_f32_32x32x16_bf16(aSH, wih, ain, 0, 0, 0);
            ahn = __builtin_amdgcn_mfma_f32_32x32x16_bf16(aHH, whh, ahn, 0, 0, 0);
            ain = __builtin_amdgcn_mfma_f32_32x32x16_bf16(aSL, wih, ain, 0, 0, 0);
            ahn = __builtin_amdgcn_mfma_f32_32x32x16_bf16(aHL, whh, ahn, 0, 0, 0);
            ain = __builtin_amdgcn_mfma_f32_32x32x16_bf16(aSH, wil, ain, 0, 0, 0);
            ahn = __builtin_amdgcn_mfma_f32_32x32x16_bf16(aHH, whl, ahn, 0, 0, 0);
        }
    }

    // ---- wave-local GRU elementwise + h write ----
    int j = j0 + cj;
    float brz0 = b_ih[j] + b_hh[j];
    float brz1 = b_ih[HD + j] + b_hh[HD + j];
    float bin_ = b_ih[2 * HD + j];
    float bhn = b_hh[2 * HD + j];
    const short* hhs = (const short*)sHH;
    const short* hls = (const short*)sHL;
    int ksj = j >> 4, halfj = (j >> 3) & 1, ej = j & 7;

#pragma unroll
    for (int r = 0; r < 16; ++r) {
        int nl = (r & 3) + 8 * (r >> 2) + 4 * kh;  // C/D row mapping (m74/m101)
        int node = n0 + nl;
        if (node < n) {
            float rr = __fdividef(1.f, 1.f + __expf(-(arz[0][r] + brz0)));
            float zz = __fdividef(1.f, 1.f + __expf(-(arz[1][r] + brz1)));
            float u = ain[r] + bin_ + rr * (ahn[r] + bhn);
            float ex = __expf(2.f * u);
            float nn2 = 1.f - __fdividef(2.f, ex + 1.f);  // tanh(u)
            int li = (ksj * 64 + nl + 32 * halfj) * 8 + ej;
            float hold = b2f(hhs[li]) + b2f(hls[li]);
            h[(size_t)node * HD + j] = (1.f - zz) * nn2 + zz * hold;
        }
    }

    // ---- xp TAIL: next-step xp for this block's 32 nodes ----
    if (x_next != nullptr) {
        int node = n0 + (t >> 3);   // 8 threads per node
        int sub = t & 7;            // cols sub*16 .. sub*16+15
        if (node < n) {
            const float* xr = x_next + (size_t)node * FIN;
            float xv[FIN];
#pragma unroll
            for (int k = 0; k < FIN; ++k) xv[k] = xr[k];
            float s = 0.f, d = 0.f;
            unsigned pk[8];
#pragma unroll
            for (int c = 0; c < 16; c += 2) {
                int c0 = sub * 16 + c, c1 = c0 + 1;
                float v0 = 0.f, v1 = 0.f;
#pragma unroll
                for (int k = 0; k < FIN; ++k) {
                    v0 += xv[k] * Wg[k * HD + c0];
                    v1 += xv[k] * Wg[k * HD + c1];
                }
                s += v0 * att_src[c0] + v1 * att_src[c1];
                d += v0 * att_dst[c0] + v1 * att_dst[c1];
                pk[c >> 1] = (unsigned)(unsigned short)f2bf(v0) |
                             ((unsigned)(unsigned short)f2bf(v1) << 16);
            }
            unsigned* dstw = xpb_next + (size_t)node * 64 + sub * 8;
            *(uint4*)(dstw) = make_uint4(pk[0], pk[1], pk[2], pk[3]);
            *(uint4*)(dstw + 4) = make_uint4(pk[4], pk[5], pk[6], pk[7]);
            // reduce a_s/a_d across the node's 8 threads (same wave)
            s += __shfl_xor(s, 1); s += __shfl_xor(s, 2); s += __shfl_xor(s, 4);
            d += __shfl_xor(d, 1); d += __shfl_xor(d, 2); d += __shfl_xor(d, 4);
            if (sub == 0) { a_s_next[node] = s; a_d_next[node] = d; }
        }
    }
}

// out[n] = h[n] . W_fc + b_fc   (one wave per node)
__global__ __launch_bounds__(256) void fc_kernel(
    const float* __restrict__ h, const float* __restrict__ W_fc,
    const float* __restrict__ b_fc, float* __restrict__ out, int n) {
    int wave = (blockIdx.x * blockDim.x + threadIdx.x) >> 6;
    int lane = threadIdx.x & 63;
    if (wave >= n) return;
    float v = h[(size_t)wave * HD + lane] * W_fc[lane] +
              h[(size_t)wave * HD + lane + 64] * W_fc[lane + 64];
#pragma unroll
    for (int off = 32; off; off >>= 1) v += __shfl_xor(v, off);
    if (lane == 0) out[wave] = v + b_fc[0];
}

// ---------------------------------------------------------------------------
extern "C" void kernel_launch(void* const* d_in, const int* in_sizes, int n_in,
                              void* d_out, int out_size, void* d_ws, size_t ws_size,
                              hipStream_t stream) {
    const float* x_seq   = (const float*)d_in[0];
    const int*   ei      = (const int*)d_in[1];
    const float* Wg      = (const float*)d_in[2];
    const float* att_src = (const float*)d_in[3];
    const float* att_dst = (const float*)d_in[4];
    const float* bias_g  = (const float*)d_in[5];
    const float* W_ih    = (const float*)d_in[6];
    const float* W_hh    = (const float*)d_in[7];
    const float* b_ih    = (const float*)d_in[8];
    const float* b_hh    = (const float*)d_in[9];
    const float* W_fc    = (const float*)d_in[10];
    const float* b_fc    = (const float*)d_in[11];
    float* out = (float*)d_out;

    const int N = NN;
    const int E = in_sizes[1] / 2;
    const int* src = ei;
    const int* dst = ei + E;

    // workspace layout
    char* w = (char*)d_ws;
    size_t off = 0;
    auto alloc = [&](size_t bytes) {
        char* p = w + off;
        off = (off + bytes + 255) & ~(size_t)255;
        return p;
    };
    int*   deg     = (int*)alloc((size_t)N * 4);
    int*   row_ptr = (int*)alloc((size_t)(N + 1) * 4);
    int*   cursor  = (int*)alloc((size_t)N * 4);
    int*   col     = (int*)alloc((size_t)(E + N) * 4);
    float* a_s0    = (float*)alloc((size_t)N * 4);
    float* a_d0    = (float*)alloc((size_t)N * 4);
    float* a_s1    = (float*)alloc((size_t)N * 4);
    float* a_d1    = (float*)alloc((size_t)N * 4);
    unsigned* xpb0 = (unsigned*)alloc((size_t)N * 64 * 4);   // bf16 xp [N][128]
    unsigned* xpb1 = (unsigned*)alloc((size_t)N * 64 * 4);
    float* hbuf    = (float*)alloc((size_t)N * HD * 4);
    short* wfrag   = (short*)alloc((size_t)3 * 4 * 8 * 4 * 64 * 8 * 2);  // 393KB

    unsigned* xpbs[2] = {xpb0, xpb1};
    float* a_ss[2] = {a_s0, a_s1};
    float* a_ds[2] = {a_d0, a_d1};

    // h0 = 0
    hipMemsetAsync(hbuf, 0, (size_t)N * HD * 4, stream);

    // CSR build + weight pack (once per launch)
    deg_init_kernel<<<(N + 255) / 256, 256, 0, stream>>>(deg, N);
    deg_count_kernel<<<(E + 255) / 256, 256, 0, stream>>>(dst, deg, E);
    scan_kernel<<<1, 1024, 0, stream>>>(deg, row_ptr, N);
    selfloop_kernel<<<(N + 255) / 256, 256, 0, stream>>>(row_ptr, cursor, col, N);
    scatter_kernel<<<(E + 255) / 256, 256, 0, stream>>>(src, dst, cursor, col, E);
    wpack_kernel<<<(24576 + 255) / 256, 256, 0, stream>>>(W_ih, W_hh, wfrag);

    int node_wave_blocks = (N * 64 + 255) / 256;  // one wave per node
    int fused_blocks = (N + 31) / 32;             // 32-node fused tiles

    // prologue: xp for t=0 into buffer 0
    xp_kernel<<<node_wave_blocks, 256, 0, stream>>>(x_seq, Wg, att_src, att_dst,
                                                    xpb0, a_s0, a_d0, N);

    for (int t = 0; t < SEQ; ++t) {
        int cur = t & 1, nxt = cur ^ 1;
        const float* xnext = (t + 1 < SEQ) ? (x_seq + (size_t)(t + 1) * N * FIN)
                                           : nullptr;
        gatgru_kernel<<<fused_blocks, 256, 0, stream>>>(
            row_ptr, col, a_ss[cur], a_ds[cur], (const short*)xpbs[cur], bias_g,
            hbuf, wfrag, b_ih, b_hh, N,
            xnext, Wg, att_src, att_dst, xpbs[nxt], a_ss[nxt], a_ds[nxt]);
    }
    fc_kernel<<<node_wave_blocks, 256, 0, stream>>>(hbuf, W_fc, b_fc, out, N);
}

// Round 7
// 5700.677 us; speedup vs baseline: 1.2083x; 1.0744x over previous
//
#include <hip/hip_runtime.h>
#include <math.h>

// Problem constants (match reference)
#define NN 50000
#define SEQ 52
#define FIN 16
#define HD 128
#define NEG_SLOPE 0.2f

typedef short bf16x8 __attribute__((ext_vector_type(8)));   // 8 bf16 (4 VGPRs)
typedef float f32x16 __attribute__((ext_vector_type(16)));  // 32x32 MFMA C/D

__device__ __forceinline__ short f2bf(float x) {
    unsigned u = __float_as_uint(x);
    u += 0x7fffu + ((u >> 16) & 1u);   // round-to-nearest-even
    return (short)(u >> 16);
}
__device__ __forceinline__ float b2f(short s) {
    return __uint_as_float(((unsigned)(unsigned short)s) << 16);
}

// ---------------------------------------------------------------------------
// CSR build kernels (run once per launch; graph is static across timesteps)
// ---------------------------------------------------------------------------
__global__ void deg_init_kernel(int* deg, int n) {
    int i = blockIdx.x * blockDim.x + threadIdx.x;
    if (i < n) deg[i] = 1;  // self-loop
}

__global__ void deg_count_kernel(const int* __restrict__ dst, int* deg, int e) {
    int i = blockIdx.x * blockDim.x + threadIdx.x;
    if (i < e) atomicAdd(&deg[dst[i]], 1);
}

__global__ __launch_bounds__(1024) void scan_kernel(const int* __restrict__ deg,
                                                    int* row_ptr, int n) {
    __shared__ int buf[1024];
    __shared__ int carry;
    int tid = threadIdx.x;
    if (tid == 0) carry = 0;
    __syncthreads();
    for (int base = 0; base < n; base += 1024) {
        int i = base + tid;
        int v = (i < n) ? deg[i] : 0;
        buf[tid] = v;
        __syncthreads();
        for (int off = 1; off < 1024; off <<= 1) {
            int t = (tid >= off) ? buf[tid - off] : 0;
            __syncthreads();
            buf[tid] += t;
            __syncthreads();
        }
        if (i < n) row_ptr[i] = carry + buf[tid] - v;  // exclusive
        __syncthreads();
        if (tid == 1023) carry += buf[1023];
        __syncthreads();
    }
    if (tid == 0) row_ptr[n] = carry;
}

__global__ void selfloop_kernel(const int* __restrict__ row_ptr, int* cursor,
                                int* col, int n) {
    int i = blockIdx.x * blockDim.x + threadIdx.x;
    if (i < n) {
        int p = row_ptr[i];
        col[p] = i;          // self-loop first
        cursor[i] = p + 1;
    }
}

__global__ void scatter_kernel(const int* __restrict__ src, const int* __restrict__ dst,
                               int* cursor, int* col, int e) {
    int i = blockIdx.x * blockDim.x + threadIdx.x;
    if (i < e) {
        int p = atomicAdd(&cursor[dst[i]], 1);
        col[p] = src[i];
    }
}

// ---------------------------------------------------------------------------
// Pack W_ih/W_hh into MFMA B-fragment order, split bf16 hi/lo.
// Index: ((((g*4+slab)*8+ks)*4+which)*64+lane)*8 shorts,
//   which: 0=ih_hi 1=ih_lo 2=hh_hi 3=hh_lo
//   col = slab*32 + (lane&31), kcol = ks*16 + (lane>>5)*8
// ---------------------------------------------------------------------------
__global__ void wpack_kernel(const float* __restrict__ Wi, const float* __restrict__ Wh,
                             short* __restrict__ wfrag) {
    int idx = blockIdx.x * blockDim.x + threadIdx.x;
    if (idx >= 3 * 4 * 8 * 4 * 64) return;
    int lane = idx & 63;
    int which = (idx >> 6) & 3;
    int ks = (idx >> 8) & 7;
    int slab = (idx >> 11) & 3;
    int g = idx >> 13;
    int col = slab * 32 + (lane & 31);
    int kcol = ks * 16 + (lane >> 5) * 8;
    const float* Wsrc = (which < 2) ? Wi : Wh;
    const float* row = Wsrc + (size_t)(g * HD + col) * HD + kcol;
    short* dstp = wfrag + (size_t)idx * 8;
    bool lo = (which & 1);
#pragma unroll
    for (int e = 0; e < 8; ++e) {
        float v = row[e];
        short hi = f2bf(v);
        dstp[e] = lo ? f2bf(v - b2f(hi)) : hi;
    }
}

// ---------------------------------------------------------------------------
// Per-timestep kernels
// ---------------------------------------------------------------------------

// xp = x_t @ Wg (stored bf16); a_s = xp.att_src ; a_d = xp.att_dst
// Used ONCE as prologue for t=0; steps 1..51 are produced by gatgru's tail.
__global__ __launch_bounds__(256) void xp_kernel(
    const float* __restrict__ x, const float* __restrict__ Wg,
    const float* __restrict__ att_src, const float* __restrict__ att_dst,
    unsigned* __restrict__ xpb, float* __restrict__ a_s, float* __restrict__ a_d, int n) {
    int wave = (blockIdx.x * blockDim.x + threadIdx.x) >> 6;
    int lane = threadIdx.x & 63;
    if (wave >= n) return;
    const float* xr = x + (size_t)wave * FIN;
    float xv[FIN];
#pragma unroll
    for (int k = 0; k < FIN; ++k) xv[k] = xr[k];
    int c0 = 2 * lane, c1 = 2 * lane + 1;
    float v0 = 0.f, v1 = 0.f;
#pragma unroll
    for (int k = 0; k < FIN; ++k) {
        v0 += xv[k] * Wg[k * HD + c0];
        v1 += xv[k] * Wg[k * HD + c1];
    }
    unsigned p = (unsigned)(unsigned short)f2bf(v0) |
                 ((unsigned)(unsigned short)f2bf(v1) << 16);
    xpb[(size_t)wave * 64 + lane] = p;
    float s = v0 * att_src[c0] + v1 * att_src[c1];
    float d = v0 * att_dst[c0] + v1 * att_dst[c1];
#pragma unroll
    for (int off = 32; off; off >>= 1) {
        s += __shfl_xor(s, off);
        d += __shfl_xor(d, off);
    }
    if (lane == 0) { a_s[wave] = s; a_d[wave] = d; }
}

// ---------------------------------------------------------------------------
// Fused GAT + GRU (+ next-step xp tail) kernel (R7).
// Block = 256 threads = 4 waves, owns 32 dst nodes (n0..n0+31).
//
// R6 counters: MfmaUtil 10 / VALUBusy 28 / HBM 15% / Occupancy 25% (=2
// blocks/CU) -> latency-bound, occupancy-limited. VGPR_Count 76 excludes
// AGPRs; accs (64) + compiler-parked weight buffers pushed combined regs
// past the 128 threshold (m69: waves/CU halves at 64/128/256).
//
// R7 change: fit combined VGPR+AGPR <= 128 -> 4 waves/SIMD (2x occupancy):
//   * GRU K-loop split into 2 passes: pass A computes r,z (2 accs = 32
//     AGPR live); pass B computes n (arz carried + ain/ahn = 64 AGPR peak).
//     Same MFMA count; LDS A-frags read twice (cheap).
//   * No manual multi-buffering -- plain loads, compiler schedules within
//     the budget (it rescheduled the manual buffers anyway per R6 regs).
//   * __launch_bounds__(256, 4) pins the allocator to <=128 combined.
// GAT phase + xp tail unchanged from R6 (both fit well under 128).
// ---------------------------------------------------------------------------
__global__ __launch_bounds__(256, 4) void gatgru_kernel(
    const int* __restrict__ row_ptr, const int* __restrict__ col,
    const float* __restrict__ a_s, const float* __restrict__ a_d,
    const short* __restrict__ xpb, const float* __restrict__ bias_g,
    float* __restrict__ h, const short* __restrict__ wfrag,
    const float* __restrict__ b_ih, const float* __restrict__ b_hh, int n,
    const float* __restrict__ x_next, const float* __restrict__ Wg,
    const float* __restrict__ att_src, const float* __restrict__ att_dst,
    unsigned* __restrict__ xpb_next, float* __restrict__ a_s_next,
    float* __restrict__ a_d_next) {
    __shared__ bf16x8 sSH[512];  // spatial hi (gat output, A-frag layout)
    __shared__ bf16x8 sSL[512];  // spatial lo
    __shared__ bf16x8 sHH[512];  // h hi
    __shared__ bf16x8 sHL[512];  // h lo

    int t = threadIdx.x;
    int lane = t & 63;
    int w = t >> 6;
    int n0 = blockIdx.x * 32;

    // ---- issue h loads early (consumed after gat phase) ----
    float h8[2][8];
#pragma unroll
    for (int q = 0; q < 2; ++q) {
        int ks = w * 2 + q;
        int row = n0 + (lane & 31);
        if (row >= n) row = n - 1;
        int kcol = ks * 16 + (lane >> 5) * 8;
        const float* hp = h + (size_t)row * HD + kcol;
        *(float4*)(h8[q]) = *(const float4*)(hp);
        *(float4*)(h8[q] + 4) = *(const float4*)(hp + 4);
    }

    // ---- GAT phase: 16-lane group per node, 2 nodes per group ----
    int g = t >> 4;          // group 0..15
    int fg = t & 15;         // feature lane: features fg*8..fg*8+7
    int glane = lane & 0x30; // group base lane within wave

#pragma unroll
    for (int nn = 0; nn < 2; ++nn) {
        int nl = g + nn * 16;   // local node 0..31
        int nd = n0 + nl;
        int sidx = (fg >> 1) * 64 + (fg & 1) * 32 + nl;  // A-frag LDS slot
        if (nd < n) {
            int start = row_ptr[nd], end = row_ptr[nd + 1];
            float ad = a_d[nd];
            float acc[8] = {0.f, 0.f, 0.f, 0.f, 0.f, 0.f, 0.f, 0.f};
            float dpart = 0.f;
            for (int base = start; base < end; base += 16) {
                int cnt = end - base;
                if (cnt > 16) cnt = 16;
                // phase 1: lane fg gathers edge base+fg
                int s = 0;
                float wgt = 0.f;
                if (fg < cnt) {
                    s = col[base + fg];
                    float e = a_s[s] + ad;
                    e = (e > 0.f) ? e : NEG_SLOPE * e;
                    wgt = __expf(e);
                }
                dpart += wgt;
                // phase 2: stream rows, 4 in flight, group-internal shfl
                for (int k = 0; k < cnt; k += 4) {
                    int si[4];
                    float wt[4];
#pragma unroll
                    for (int u = 0; u < 4; ++u) {
                        int c = k + u;
                        int cc = (c < cnt) ? c : 0;
                        si[u] = __shfl(s, glane | cc);
                        wt[u] = __shfl(wgt, glane | cc);
                        if (c >= cnt) wt[u] = 0.f;
                    }
                    bf16x8 r[4];
#pragma unroll
                    for (int u = 0; u < 4; ++u)
                        r[u] = *(const bf16x8*)(xpb + (size_t)si[u] * HD + fg * 8);
#pragma unroll
                    for (int u = 0; u < 4; ++u)
#pragma unroll
                        for (int j = 0; j < 8; ++j) acc[j] += wt[u] * b2f(r[u][j]);
                }
            }
            // denom reduce across the 16-lane group
            dpart += __shfl_xor(dpart, 8);
            dpart += __shfl_xor(dpart, 4);
            dpart += __shfl_xor(dpart, 2);
            dpart += __shfl_xor(dpart, 1);
            float inv = __fdividef(1.f, dpart);
            bf16x8 sh, sl;
#pragma unroll
            for (int j = 0; j < 8; ++j) {
                float o = acc[j] * inv + bias_g[fg * 8 + j];
                o = fmaxf(o, 0.f);
                short hi = f2bf(o);
                sh[j] = hi;
                sl[j] = f2bf(o - b2f(hi));
            }
            sSH[sidx] = sh;
            sSL[sidx] = sl;
        } else {
            bf16x8 z;
#pragma unroll
            for (int j = 0; j < 8; ++j) z[j] = 0;
            sSH[sidx] = z;
            sSL[sidx] = z;
        }
    }

    // ---- convert + write h tiles (loads drained long ago) ----
#pragma unroll
    for (int q = 0; q < 2; ++q) {
        int ks = w * 2 + q;
        bf16x8 hh, hl;
#pragma unroll
        for (int j = 0; j < 8; ++j) {
            short b = f2bf(h8[q][j]);
            hh[j] = b;
            hl[j] = f2bf(h8[q][j] - b2f(b));
        }
        int li = ks * 64 + lane;
        sHH[li] = hh;
        sHL[li] = hl;
    }
    __syncthreads();

    // ---- GRU phase: 2-pass K-loop (R7) ----
    int j0 = w * 32;
    int cj = lane & 31;       // column within wave's 32-col slab
    int kh = lane >> 5;       // k-half for frags

    // fragment-ordered weight base for this wave: + g*65536 + ks*2048 + which*512
    const short* wb = wfrag + (size_t)w * 16384 + (size_t)lane * 8;

    // ---- pass A: r and z gates (merged ih+hh accumulators) ----
    f32x16 arz0, arz1;
#pragma unroll
    for (int r = 0; r < 16; ++r) { arz0[r] = 0.f; arz1[r] = 0.f; }

#pragma unroll
    for (int ks = 0; ks < 8; ++ks) {
        int li = ks * 64 + lane;
        bf16x8 aSH = sSH[li];
        bf16x8 aSL = sSL[li];
        bf16x8 aHH = sHH[li];
        bf16x8 aHL = sHL[li];
        {
            const short* p = wb + 0 * 65536 + ks * 2048;
            bf16x8 wih = *(const bf16x8*)(p);
            bf16x8 wil = *(const bf16x8*)(p + 512);
            bf16x8 whh = *(const bf16x8*)(p + 1024);
            bf16x8 whl = *(const bf16x8*)(p + 1536);
            arz0 = __builtin_amdgcn_mfma_f32_32x32x16_bf16(aSH, wih, arz0, 0, 0, 0);
            arz0 = __builtin_amdgcn_mfma_f32_32x32x16_bf16(aHH, whh, arz0, 0, 0, 0);
            arz0 = __builtin_amdgcn_mfma_f32_32x32x16_bf16(aSL, wih, arz0, 0, 0, 0);
            arz0 = __builtin_amdgcn_mfma_f32_32x32x16_bf16(aHL, whh, arz0, 0, 0, 0);
            arz0 = __builtin_amdgcn_mfma_f32_32x32x16_bf16(aSH, wil, arz0, 0, 0, 0);
            arz0 = __builtin_amdgcn_mfma_f32_32x32x16_bf16(aHH, whl, arz0, 0, 0, 0);
        }
        {
            const short* p = wb + 1 * 65536 + ks * 2048;
            bf16x8 wih = *(const bf16x8*)(p);
            bf16x8 wil = *(const bf16x8*)(p + 512);
            bf16x8 whh = *(const bf16x8*)(p + 1024);
            bf16x8 whl = *(const bf16x8*)(p + 1536);
            arz1 = __builtin_amdgcn_mfma_f32_32x32x16_bf16(aSH, wih, arz1, 0, 0, 0);
            arz1 = __builtin_amdgcn_mfma_f32_32x32x16_bf16(aHH, whh, arz1, 0, 0, 0);
            arz1 = __builtin_amdgcn_mfma_f32_32x32x16_bf16(aSL, wih, arz1, 0, 0, 0);
            arz1 = __builtin_amdgcn_mfma_f32_32x32x16_bf16(aHL, whh, arz1, 0, 0, 0);
            arz1 = __builtin_amdgcn_mfma_f32_32x32x16_bf16(aSH, wil, arz1, 0, 0, 0);
            arz1 = __builtin_amdgcn_mfma_f32_32x32x16_bf16(aHH, whl, arz1, 0, 0, 0);
        }
    }

    // ---- pass B: n gate (separate ih/hh accumulators; r gates h_n) ----
    f32x16 ain, ahn;
#pragma unroll
    for (int r = 0; r < 16; ++r) { ain[r] = 0.f; ahn[r] = 0.f; }

#pragma unroll
    for (int ks = 0; ks < 8; ++ks) {
        int li = ks * 64 + lane;
        bf16x8 aSH = sSH[li];
        bf16x8 aSL = sSL[li];
        bf16x8 aHH = sHH[li];
        bf16x8 aHL = sHL[li];
        const short* p = wb + 2 * 65536 + ks * 2048;
        bf16x8 wih = *(const bf16x8*)(p);
        bf16x8 wil = *(const bf16x8*)(p + 512);
        bf16x8 whh = *(const bf16x8*)(p + 1024);
        bf16x8 whl = *(const bf16x8*)(p + 1536);
        ain = __builtin_amdgcn_mfma_f32_32x32x16_bf16(aSH, wih, ain, 0, 0, 0);
        ahn = __builtin_amdgcn_mfma_f32_32x32x16_bf16(aHH, whh, ahn, 0, 0, 0);
        ain = __builtin_amdgcn_mfma_f32_32x32x16_bf16(aSL, wih, ain, 0, 0, 0);
        ahn = __builtin_amdgcn_mfma_f32_32x32x16_bf16(aHL, whh, ahn, 0, 0, 0);
        ain = __builtin_amdgcn_mfma_f32_32x32x16_bf16(aSH, wil, ain, 0, 0, 0);
        ahn = __builtin_amdgcn_mfma_f32_32x32x16_bf16(aHH, whl, ahn, 0, 0, 0);
    }

    // ---- wave-local GRU elementwise + h write ----
    int j = j0 + cj;
    float brz0 = b_ih[j] + b_hh[j];
    float brz1 = b_ih[HD + j] + b_hh[HD + j];
    float bin_ = b_ih[2 * HD + j];
    float bhn = b_hh[2 * HD + j];
    const short* hhs = (const short*)sHH;
    const short* hls = (const short*)sHL;
    int ksj = j >> 4, halfj = (j >> 3) & 1, ej = j & 7;

#pragma unroll
    for (int r = 0; r < 16; ++r) {
        int nl = (r & 3) + 8 * (r >> 2) + 4 * kh;  // C/D row mapping (m74/m101)
        int node = n0 + nl;
        if (node < n) {
            float rr = __fdividef(1.f, 1.f + __expf(-(arz0[r] + brz0)));
            float zz = __fdividef(1.f, 1.f + __expf(-(arz1[r] + brz1)));
            float u = ain[r] + bin_ + rr * (ahn[r] + bhn);
            float ex = __expf(2.f * u);
            float nn2 = 1.f - __fdividef(2.f, ex + 1.f);  // tanh(u)
            int li = (ksj * 64 + nl + 32 * halfj) * 8 + ej;
            float hold = b2f(hhs[li]) + b2f(hls[li]);
            h[(size_t)node * HD + j] = (1.f - zz) * nn2 + zz * hold;
        }
    }

    // ---- xp TAIL: next-step xp for this block's 32 nodes ----
    if (x_next != nullptr) {
        int node = n0 + (t >> 3);   // 8 threads per node
        int sub = t & 7;            // cols sub*16 .. sub*16+15
        if (node < n) {
            const float* xr = x_next + (size_t)node * FIN;
            float xv[FIN];
#pragma unroll
            for (int k = 0; k < FIN; ++k) xv[k] = xr[k];
            float s = 0.f, d = 0.f;
            unsigned pk[8];
#pragma unroll
            for (int c = 0; c < 16; c += 2) {
                int c0 = sub * 16 + c, c1 = c0 + 1;
                float v0 = 0.f, v1 = 0.f;
#pragma unroll
                for (int k = 0; k < FIN; ++k) {
                    v0 += xv[k] * Wg[k * HD + c0];
                    v1 += xv[k] * Wg[k * HD + c1];
                }
                s += v0 * att_src[c0] + v1 * att_src[c1];
                d += v0 * att_dst[c0] + v1 * att_dst[c1];
                pk[c >> 1] = (unsigned)(unsigned short)f2bf(v0) |
                             ((unsigned)(unsigned short)f2bf(v1) << 16);
            }
            unsigned* dstw = xpb_next + (size_t)node * 64 + sub * 8;
            *(uint4*)(dstw) = make_uint4(pk[0], pk[1], pk[2], pk[3]);
            *(uint4*)(dstw + 4) = make_uint4(pk[4], pk[5], pk[6], pk[7]);
            // reduce a_s/a_d across the node's 8 threads (same wave)
            s += __shfl_xor(s, 1); s += __shfl_xor(s, 2); s += __shfl_xor(s, 4);
            d += __shfl_xor(d, 1); d += __shfl_xor(d, 2); d += __shfl_xor(d, 4);
            if (sub == 0) { a_s_next[node] = s; a_d_next[node] = d; }
        }
    }
}

// out[n] = h[n] . W_fc + b_fc   (one wave per node)
__global__ __launch_bounds__(256) void fc_kernel(
    const float* __restrict__ h, const float* __restrict__ W_fc,
    const float* __restrict__ b_fc, float* __restrict__ out, int n) {
    int wave = (blockIdx.x * blockDim.x + threadIdx.x) >> 6;
    int lane = threadIdx.x & 63;
    if (wave >= n) return;
    float v = h[(size_t)wave * HD + lane] * W_fc[lane] +
              h[(size_t)wave * HD + lane + 64] * W_fc[lane + 64];
#pragma unroll
    for (int off = 32; off; off >>= 1) v += __shfl_xor(v, off);
    if (lane == 0) out[wave] = v + b_fc[0];
}

// ---------------------------------------------------------------------------
extern "C" void kernel_launch(void* const* d_in, const int* in_sizes, int n_in,
                              void* d_out, int out_size, void* d_ws, size_t ws_size,
                              hipStream_t stream) {
    const float* x_seq   = (const float*)d_in[0];
    const int*   ei      = (const int*)d_in[1];
    const float* Wg      = (const float*)d_in[2];
    const float* att_src = (const float*)d_in[3];
    const float* att_dst = (const float*)d_in[4];
    const float* bias_g  = (const float*)d_in[5];
    const float* W_ih    = (const float*)d_in[6];
    const float* W_hh    = (const float*)d_in[7];
    const float* b_ih    = (const float*)d_in[8];
    const float* b_hh    = (const float*)d_in[9];
    const float* W_fc    = (const float*)d_in[10];
    const float* b_fc    = (const float*)d_in[11];
    float* out = (float*)d_out;

    const int N = NN;
    const int E = in_sizes[1] / 2;
    const int* src = ei;
    const int* dst = ei + E;

    // workspace layout
    char* w = (char*)d_ws;
    size_t off = 0;
    auto alloc = [&](size_t bytes) {
        char* p = w + off;
        off = (off + bytes + 255) & ~(size_t)255;
        return p;
    };
    int*   deg     = (int*)alloc((size_t)N * 4);
    int*   row_ptr = (int*)alloc((size_t)(N + 1) * 4);
    int*   cursor  = (int*)alloc((size_t)N * 4);
    int*   col     = (int*)alloc((size_t)(E + N) * 4);
    float* a_s0    = (float*)alloc((size_t)N * 4);
    float* a_d0    = (float*)alloc((size_t)N * 4);
    float* a_s1    = (float*)alloc((size_t)N * 4);
    float* a_d1    = (float*)alloc((size_t)N * 4);
    unsigned* xpb0 = (unsigned*)alloc((size_t)N * 64 * 4);   // bf16 xp [N][128]
    unsigned* xpb1 = (unsigned*)alloc((size_t)N * 64 * 4);
    float* hbuf    = (float*)alloc((size_t)N * HD * 4);
    short* wfrag   = (short*)alloc((size_t)3 * 4 * 8 * 4 * 64 * 8 * 2);  // 393KB

    unsigned* xpbs[2] = {xpb0, xpb1};
    float* a_ss[2] = {a_s0, a_s1};
    float* a_ds[2] = {a_d0, a_d1};

    // h0 = 0
    hipMemsetAsync(hbuf, 0, (size_t)N * HD * 4, stream);

    // CSR build + weight pack (once per launch)
    deg_init_kernel<<<(N + 255) / 256, 256, 0, stream>>>(deg, N);
    deg_count_kernel<<<(E + 255) / 256, 256, 0, stream>>>(dst, deg, E);
    scan_kernel<<<1, 1024, 0, stream>>>(deg, row_ptr, N);
    selfloop_kernel<<<(N + 255) / 256, 256, 0, stream>>>(row_ptr, cursor, col, N);
    scatter_kernel<<<(E + 255) / 256, 256, 0, stream>>>(src, dst, cursor, col, E);
    wpack_kernel<<<(24576 + 255) / 256, 256, 0, stream>>>(W_ih, W_hh, wfrag);

    int node_wave_blocks = (N * 64 + 255) / 256;  // one wave per node
    int fused_blocks = (N + 31) / 32;             // 32-node fused tiles

    // prologue: xp for t=0 into buffer 0
    xp_kernel<<<node_wave_blocks, 256, 0, stream>>>(x_seq, Wg, att_src, att_dst,
                                                    xpb0, a_s0, a_d0, N);

    for (int t = 0; t < SEQ; ++t) {
        int cur = t & 1, nxt = cur ^ 1;
        const float* xnext = (t + 1 < SEQ) ? (x_seq + (size_t)(t + 1) * N * FIN)
                                           : nullptr;
        gatgru_kernel<<<fused_blocks, 256, 0, stream>>>(
            row_ptr, col, a_ss[cur], a_ds[cur], (const short*)xpbs[cur], bias_g,
            hbuf, wfrag, b_ih, b_hh, N,
            xnext, Wg, att_src, att_dst, xpbs[nxt], a_ss[nxt], a_ds[nxt]);
    }
    fc_kernel<<<node_wave_blocks, 256, 0, stream>>>(hbuf, W_fc, b_fc, out, N);
}